// Round 2
// baseline (99.054 us; speedup 1.0000x reference)
//
#include <hip/hip_runtime.h>
#include <stdint.h>

typedef __attribute__((ext_vector_type(8))) short bfrag_t;   // 8 bf16
typedef __attribute__((ext_vector_type(4))) float floatx4;   // MFMA acc

// ---------------- ws layout (bytes) ----------------
#define WFRAG_OFF   0            // bf16 [16kt][18nt][64lane][8j]   = 294912
#define GB_OFF      294912       // f32 [32][128]                   = 16384
#define BU_OFF      311296       // f32 [128]
#define BS_OFF      311808       // f32 [32]
#define ACCW_OFF    311936       // f32 [32][128]
#define ACCG_OFF    328320       // f32 [32][128]
#define MEMFRAG_OFF 344704       // bf16 frag [8nt][64lane][8j]     = 8192
#define CNT_OFF     352896       // int

// ---------------- main-kernel LDS layout (bytes) ----------------
#define ATILE_OFF   0            // bf16 swizzled [32r][512k] = 32768 (dead after GEMM)
#define U_OFF       0            // f32 [32][128] = 16384  (overlay)
#define RC_OFF      16384        // f32 [32][128] = 16384  (overlay)
#define XPFRAG_LDS  32768        // bf16 frag [8nt][64lane][8j] = 8192
#define SC_OFF      40960        // f32 [32][32] = 4096
#define PR_OFF      45056        // bf16 [32][40] = 2560
#define PRT_OFF     47616        // bf16 [32][40] = 2560
#define LDS_TOTAL   50176

__device__ __forceinline__ unsigned short f2bf(float f) {
    unsigned u = __float_as_uint(f);
    u += 0x7fffu + ((u >> 16) & 1u);
    return (unsigned short)(u >> 16);
}
__device__ __forceinline__ float sigm(float v) {
    return __builtin_amdgcn_rcpf(1.0f + __expf(-v));
}
__device__ __forceinline__ void writefrag(unsigned short* wf, int k, int n, float v) {
    int kt = k >> 5, kk = k & 31;
    int lane = (n & 15) | ((kk >> 3) << 4);
    wf[(((kt * 18) + (n >> 4)) * 64 + lane) * 8 + (kk & 7)] = f2bf(v);
}

// ---------------- prep: frag weights, gate base, biases, zeroing ----------------
__global__ __launch_bounds__(256) void prep_kernel(
    const float* __restrict__ memv, const float* __restrict__ w_in,
    const float* __restrict__ b_in, const float* __restrict__ w_gate,
    const float* __restrict__ b_gate, unsigned char* __restrict__ ws)
{
    int bid = blockIdx.x, t = threadIdx.x;
    unsigned short* wfrag = (unsigned short*)(ws + WFRAG_OFF);
    const float* wg2 = w_gate + 128 * 128;   // rows 128..255 of w_gate

    if (bid < 256) {
        // combined weight: [w_in | w_in@W2 | w_in@mem^T] for 2 k-rows
        __shared__ float wrow[2][128];
        int k0 = bid * 2;
        wrow[t >> 7][t & 127] = w_in[(size_t)(k0 + (t >> 7)) * 128 + (t & 127)];
        __syncthreads();
        for (int kl = 0; kl < 2; ++kl) {
            int k = k0 + kl;
            float v;
            if (t < 128) {
                v = wrow[kl][t];
            } else {
                int d = t - 128;
                float acc = 0.f;
                #pragma unroll 8
                for (int j = 0; j < 128; ++j) acc += wrow[kl][j] * wg2[j * 128 + d];
                v = acc;
            }
            writefrag(wfrag, k, t, v);
            if (t < 32) {
                float acc = 0.f;
                #pragma unroll 8
                for (int d = 0; d < 128; ++d) acc += wrow[kl][d] * memv[t * 128 + d];
                writefrag(wfrag, k, 256 + t, acc);
            }
        }
    } else if (bid < 272) {
        // gb[s][d] = b_gate[d] + mem[s]@W1[:,d]
        int idx = (bid - 256) * 256 + t;      // 0..4095
        int s = idx >> 7, d = idx & 127;
        float acc = b_gate[d];
        #pragma unroll 8
        for (int k = 0; k < 128; ++k) acc += memv[s * 128 + k] * w_gate[k * 128 + d];
        ((float*)(ws + GB_OFF))[idx] = acc;
    } else {
        // biases, mem fragments, zero accumulators + counter
        if (t < 128) {
            float acc = 0.f;
            #pragma unroll 8
            for (int j = 0; j < 128; ++j) acc += b_in[j] * wg2[j * 128 + t];
            ((float*)(ws + BU_OFF))[t] = acc;
        }
        if (t < 32) {
            float acc = 0.f;
            #pragma unroll 8
            for (int d = 0; d < 128; ++d) acc += b_in[d] * memv[t * 128 + d];
            ((float*)(ws + BS_OFF))[t] = acc;
        }
        unsigned short* mfr = (unsigned short*)(ws + MEMFRAG_OFF);
        for (int idx = t; idx < 4096; idx += 256) {
            int s = idx >> 7, d = idx & 127;
            mfr[((d >> 4) * 64 + ((d & 15) | (((s >> 3) & 3) << 4))) * 8 + (s & 7)]
                = f2bf(memv[idx]);
        }
        float* az = (float*)(ws + ACCW_OFF);
        for (int i = t; i < 8192; i += 256) az[i] = 0.f;
        if (t == 0) *(int*)(ws + CNT_OFF) = 0;
    }
}

// ---------------- main fused kernel: 512 blocks x 256 threads, 32 rows ----------------
__global__ __launch_bounds__(256, 2) void main_kernel(
    const float* __restrict__ x, const float* __restrict__ memv,
    const float* __restrict__ ln_g, const float* __restrict__ ln_b,
    const float* __restrict__ b_in, unsigned char* __restrict__ ws,
    float* __restrict__ out)
{
    __shared__ char smem[LDS_TOTAL] __attribute__((aligned(16)));
    __shared__ int lastflag;

    int tid = threadIdx.x;
    int w = tid >> 6, l = tid & 63;
    int lane_lo = l & 15, lane_hi = l >> 4;
    int row_base = blockIdx.x * 32;

    // ===== Phase 1: LayerNorm -> swizzled bf16 A tile [32][512] =====
    const float4* x4 = (const float4*)x;
    float4 g0 = ((const float4*)ln_g)[l];
    float4 g1 = ((const float4*)ln_g)[l + 64];
    float4 q0 = ((const float4*)ln_b)[l];
    float4 q1 = ((const float4*)ln_b)[l + 64];
    for (int i = 0; i < 8; ++i) {
        int r = w * 8 + i;
        float4 xa = x4[(size_t)(row_base + r) * 128 + l];
        float4 xb = x4[(size_t)(row_base + r) * 128 + 64 + l];
        float s1 = xa.x + xa.y + xa.z + xa.w + xb.x + xb.y + xb.z + xb.w;
        float s2 = xa.x*xa.x + xa.y*xa.y + xa.z*xa.z + xa.w*xa.w
                 + xb.x*xb.x + xb.y*xb.y + xb.z*xb.z + xb.w*xb.w;
        #pragma unroll
        for (int m = 1; m < 64; m <<= 1) {
            s1 += __shfl_xor(s1, m);
            s2 += __shfl_xor(s2, m);
        }
        float mu = s1 * (1.f / 512.f);
        float var = s2 * (1.f / 512.f) - mu * mu;
        float rs = rsqrtf(var + 1e-5f);
        float ya0 = (xa.x - mu) * rs * g0.x + q0.x;
        float ya1 = (xa.y - mu) * rs * g0.y + q0.y;
        float ya2 = (xa.z - mu) * rs * g0.z + q0.z;
        float ya3 = (xa.w - mu) * rs * g0.w + q0.w;
        float yb0 = (xb.x - mu) * rs * g1.x + q1.x;
        float yb1 = (xb.y - mu) * rs * g1.y + q1.y;
        float yb2 = (xb.z - mu) * rs * g1.z + q1.z;
        float yb3 = (xb.w - mu) * rs * g1.w + q1.w;
        unsigned long long pa =
            (unsigned long long)f2bf(ya0) | ((unsigned long long)f2bf(ya1) << 16) |
            ((unsigned long long)f2bf(ya2) << 32) | ((unsigned long long)f2bf(ya3) << 48);
        unsigned long long pb =
            (unsigned long long)f2bf(yb0) | ((unsigned long long)f2bf(yb1) << 16) |
            ((unsigned long long)f2bf(yb2) << 32) | ((unsigned long long)f2bf(yb3) << 48);
        int sw = (r & 7) << 4;
        *(unsigned long long*)(smem + ((r * 1024 + l * 8) ^ sw)) = pa;
        *(unsigned long long*)(smem + ((r * 1024 + 512 + l * 8) ^ sw)) = pb;
    }
    __syncthreads();

    // ===== Phase 2: MFMA GEMM [32 x 512] @ [512 x 288] =====
    // wave w owns n-tiles {w, w+4, w+8, w+12} (+16+w if w<2), both 16-row m-tiles
    int cnt = (w < 2) ? 5 : 4;
    int nts[5];
    #pragma unroll
    for (int i = 0; i < 4; ++i) nts[i] = w + i * 4;
    nts[4] = 16 + w;

    const bfrag_t* wf = (const bfrag_t*)(ws + WFRAG_OFF);
    int swa = (l & 7) << 4;
    int ab0 = (lane_lo) * 1024 + (lane_hi << 4);
    int ab1 = (16 + lane_lo) * 1024 + (lane_hi << 4);

    floatx4 acc[5][2];
    #pragma unroll
    for (int i = 0; i < 5; ++i)
        #pragma unroll
        for (int mt = 0; mt < 2; ++mt)
            acc[i][mt] = (floatx4){0.f, 0.f, 0.f, 0.f};

    bfrag_t acur0, acur1, anxt0, anxt1, bcur[5], bnxt[5];
    acur0 = *(const bfrag_t*)(smem + (ab0 ^ swa));
    acur1 = *(const bfrag_t*)(smem + (ab1 ^ swa));
    #pragma unroll
    for (int i = 0; i < 5; ++i)
        if (i < cnt) bcur[i] = wf[(0 * 18 + nts[i]) * 64 + l];

    for (int kt = 0; kt < 16; ++kt) {
        if (kt < 15) {
            int ko = (kt + 1) * 64;
            anxt0 = *(const bfrag_t*)(smem + ((ab0 + ko) ^ swa));
            anxt1 = *(const bfrag_t*)(smem + ((ab1 + ko) ^ swa));
            #pragma unroll
            for (int i = 0; i < 5; ++i)
                if (i < cnt) bnxt[i] = wf[((kt + 1) * 18 + nts[i]) * 64 + l];
        }
        #pragma unroll
        for (int i = 0; i < 5; ++i) {
            if (i < cnt) {
                acc[i][0] = __builtin_amdgcn_mfma_f32_16x16x32_bf16(acur0, bcur[i], acc[i][0], 0, 0, 0);
                acc[i][1] = __builtin_amdgcn_mfma_f32_16x16x32_bf16(acur1, bcur[i], acc[i][1], 0, 0, 0);
            }
        }
        acur0 = anxt0; acur1 = anxt1;
        #pragma unroll
        for (int i = 0; i < 5; ++i)
            if (i < cnt) bcur[i] = bnxt[i];
    }
    __syncthreads();   // A tile dead; region reused below

    // ===== Phase 3: epilogue -> xpfrag (bf16 frag), u (f32), scores (f32) =====
    {
        const float* bu = (const float*)(ws + BU_OFF);
        const float* bs = (const float*)(ws + BS_OFF);
        #pragma unroll
        for (int i = 0; i < 5; ++i) {
            if (i < cnt) {
                int n = nts[i] * 16 + lane_lo;
                #pragma unroll
                for (int mt = 0; mt < 2; ++mt) {
                    #pragma unroll
                    for (int r4 = 0; r4 < 4; ++r4) {
                        int row = mt * 16 + lane_hi * 4 + r4;
                        float v = acc[i][mt][r4];
                        if (i < 2) {                 // x_proj tiles 0..7 -> frag layout
                            float val = v + b_in[n];
                            int addr = XPFRAG_LDS +
                                (((n >> 4) * 64 + ((n & 15) | (((row >> 3) & 3) << 4))) * 8
                                 + (row & 7)) * 2;
                            *(unsigned short*)(smem + addr) = f2bf(val);
                        } else if (i < 4) {          // u tiles 8..15
                            int d = n - 128;
                            *(float*)(smem + U_OFF + (row * 128 + d) * 4) = v + bu[d];
                        } else {                     // score tiles 16..17
                            int s = n - 256;
                            *(float*)(smem + SC_OFF + (row * 32 + s) * 4) = v + bs[s];
                        }
                    }
                }
            }
        }
    }
    __syncthreads();

    // ===== Phase 4: softmax (8 rows per wave), store probs + probs^T (bf16) =====
    for (int i = 0; i < 8; ++i) {
        int r = w * 8 + i;
        int s = l & 31;
        float sc = *(const float*)(smem + SC_OFF + (r * 32 + s) * 4);
        float mx = sc;
        #pragma unroll
        for (int m = 1; m < 32; m <<= 1) mx = fmaxf(mx, __shfl_xor(mx, m));
        float e = __expf(sc - mx);
        float sum = e;
        #pragma unroll
        for (int m = 1; m < 32; m <<= 1) sum += __shfl_xor(sum, m);
        float p = e * __builtin_amdgcn_rcpf(sum);
        if (l < 32) {
            unsigned short pb = f2bf(p);
            *(unsigned short*)(smem + PR_OFF + (r * 40 + s) * 2) = pb;
            *(unsigned short*)(smem + PRT_OFF + (s * 40 + r) * 2) = pb;
        }
    }
    __syncthreads();

    // ===== Phase 5: read-GEMM (probs@mem -> rc) + write-GEMM (probs^T@xp -> atomics) =====
    {
        bfrag_t pa[2], pat[2], bm[2], bx[2];
        #pragma unroll
        for (int mt = 0; mt < 2; ++mt) {
            pa[mt]  = *(const bfrag_t*)(smem + PR_OFF  + ((mt * 16 + lane_lo) * 40 + lane_hi * 8) * 2);
            pat[mt] = *(const bfrag_t*)(smem + PRT_OFF + ((mt * 16 + lane_lo) * 40 + lane_hi * 8) * 2);
        }
        const bfrag_t* mf = (const bfrag_t*)(ws + MEMFRAG_OFF);
        #pragma unroll
        for (int j = 0; j < 2; ++j) {
            int nt = 2 * w + j;
            bm[j] = mf[nt * 64 + l];
            bx[j] = *(const bfrag_t*)(smem + XPFRAG_LDS + (nt * 64 + l) * 16);
        }
        floatx4 rca[2][2], wa[2][2];
        #pragma unroll
        for (int j = 0; j < 2; ++j)
            #pragma unroll
            for (int mt = 0; mt < 2; ++mt) {
                rca[j][mt] = (floatx4){0.f, 0.f, 0.f, 0.f};
                wa[j][mt]  = (floatx4){0.f, 0.f, 0.f, 0.f};
                rca[j][mt] = __builtin_amdgcn_mfma_f32_16x16x32_bf16(pa[mt],  bm[j], rca[j][mt], 0, 0, 0);
                wa[j][mt]  = __builtin_amdgcn_mfma_f32_16x16x32_bf16(pat[mt], bx[j], wa[j][mt], 0, 0, 0);
            }
        float* accw = (float*)(ws + ACCW_OFF);
        #pragma unroll
        for (int j = 0; j < 2; ++j) {
            int nc = (2 * w + j) * 16 + lane_lo;
            #pragma unroll
            for (int mt = 0; mt < 2; ++mt) {
                #pragma unroll
                for (int r4 = 0; r4 < 4; ++r4) {
                    int row = mt * 16 + lane_hi * 4 + r4;
                    *(float*)(smem + RC_OFF + (row * 128 + nc) * 4) = rca[j][mt][r4];
                    __hip_atomic_fetch_add(&accw[row * 128 + nc], wa[j][mt][r4],
                                           __ATOMIC_RELAXED, __HIP_MEMORY_SCOPE_AGENT);
                }
            }
        }
    }
    __syncthreads();

    // ===== Phase 6: rc writeback (coalesced), gate accumulation, last-block finalize =====
    {
        const float4* rc4 = (const float4*)(smem + RC_OFF);
        float4* out4 = (float4*)out;
        #pragma unroll
        for (int q = 0; q < 4; ++q) {
            int idx = q * 256 + tid;              // 1024 float4s = 32 rows x 32
            int row = idx >> 5, c4 = idx & 31;
            out4[(size_t)(row_base + row) * 32 + c4] = rc4[idx];
        }
    }
    {
        int sbase = w * 8;
        const float* gb = (const float*)(ws + GB_OFF);
        float gbr0[8], gbr1[8], ag0[8], ag1[8];
        #pragma unroll
        for (int si = 0; si < 8; ++si) {
            gbr0[si] = gb[(sbase + si) * 128 + l];
            gbr1[si] = gb[(sbase + si) * 128 + l + 64];
            ag0[si] = 0.f; ag1[si] = 0.f;
        }
        for (int r = 0; r < 32; ++r) {
            float uv0 = *(const float*)(smem + U_OFF + (r * 128 + l) * 4);
            float uv1 = *(const float*)(smem + U_OFF + (r * 128 + l + 64) * 4);
            #pragma unroll
            for (int si = 0; si < 8; ++si) {
                ag0[si] += sigm(gbr0[si] + uv0);
                ag1[si] += sigm(gbr1[si] + uv1);
            }
        }
        float* accg = (float*)(ws + ACCG_OFF);
        #pragma unroll
        for (int si = 0; si < 8; ++si) {
            __hip_atomic_fetch_add(&accg[(sbase + si) * 128 + l],      ag0[si],
                                   __ATOMIC_RELAXED, __HIP_MEMORY_SCOPE_AGENT);
            __hip_atomic_fetch_add(&accg[(sbase + si) * 128 + l + 64], ag1[si],
                                   __ATOMIC_RELAXED, __HIP_MEMORY_SCOPE_AGENT);
        }
    }
    __threadfence();
    if (tid == 0) {
        int old = __hip_atomic_fetch_add((int*)(ws + CNT_OFF), 1,
                                         __ATOMIC_ACQ_REL, __HIP_MEMORY_SCOPE_AGENT);
        lastflag = (old == (int)gridDim.x - 1);
    }
    __syncthreads();
    if (lastflag) {
        float* accw = (float*)(ws + ACCW_OFF);
        float* accg = (float*)(ws + ACCG_OFF);
        for (int i = tid; i < 4096; i += 256) {
            float ag = __hip_atomic_load(&accg[i], __ATOMIC_RELAXED, __HIP_MEMORY_SCOPE_AGENT)
                       * (1.f / 16384.f);
            float aw = __hip_atomic_load(&accw[i], __ATOMIC_RELAXED, __HIP_MEMORY_SCOPE_AGENT)
                       * (1.f / 16384.f);
            out[2097152 + i] = memv[i] * (1.f - ag) + aw * ag;
        }
    }
}

// ---------------- launcher ----------------
extern "C" void kernel_launch(void* const* d_in, const int* in_sizes, int n_in,
                              void* d_out, int out_size, void* d_ws, size_t ws_size,
                              hipStream_t stream)
{
    (void)in_sizes; (void)n_in; (void)out_size; (void)ws_size;
    const float* x      = (const float*)d_in[0];
    const float* memv   = (const float*)d_in[1];
    const float* ln_g   = (const float*)d_in[2];
    const float* ln_b   = (const float*)d_in[3];
    const float* w_in   = (const float*)d_in[4];
    const float* b_in   = (const float*)d_in[5];
    const float* w_gate = (const float*)d_in[6];
    const float* b_gate = (const float*)d_in[7];
    float* out = (float*)d_out;
    unsigned char* ws = (unsigned char*)d_ws;

    hipLaunchKernelGGL(prep_kernel, dim3(273), dim3(256), 0, stream,
                       memv, w_in, b_in, w_gate, b_gate, ws);
    hipLaunchKernelGGL(main_kernel, dim3(512), dim3(256), 0, stream,
                       x, memv, ln_g, ln_b, b_in, ws, out);
}

// Round 3
// 64.037 us; speedup vs baseline: 1.5468x; 1.5468x over previous
//
#include <hip/hip_runtime.h>
#include <stdint.h>

typedef __attribute__((ext_vector_type(8))) short bfrag_t;   // 8 bf16
typedef __attribute__((ext_vector_type(4))) float floatx4;   // MFMA acc

// ---------------- ws layout (bytes) ----------------
#define WFRAG_OFF   0            // bf16 [16kt][18nt][64lane][8j]   = 294912
#define GB_OFF      294912       // f32 [32][128]                   = 16384
#define BU_OFF      311296       // f32 [128]
#define BS_OFF      311808       // f32 [32]
#define MEMFRAG_OFF 311936       // bf16 frag [8nt][64lane][8j]     = 8192
#define ACC_OFF     327680       // NCOPY x (accw[4096] | accg[4096]) f32 = NCOPY*32768
#define NCOPY       32           // 1 MiB of accumulator copies

// ---------------- main-kernel LDS layout (bytes) ----------------
#define U_OFF       0            // f32 [32][128] = 16384  (overlays A tile)
#define RC_OFF      16384        // f32 [32][128] = 16384  (overlay)
#define XPFRAG_LDS  32768        // bf16 frag [8nt][64lane][8j] = 8192
#define SC_OFF      40960        // f32 [32][32] = 4096
#define PR_OFF      45056        // bf16 [32][40] = 2560
#define PRT_OFF     47616        // bf16 [32][40] = 2560
#define LDS_TOTAL   50176

__device__ __forceinline__ unsigned short f2bf(float f) {
    unsigned u = __float_as_uint(f);
    u += 0x7fffu + ((u >> 16) & 1u);
    return (unsigned short)(u >> 16);
}
__device__ __forceinline__ float sigm(float v) {
    return __builtin_amdgcn_rcpf(1.0f + __expf(-v));
}
__device__ __forceinline__ void writefrag(unsigned short* wf, int k, int n, float v) {
    int kt = k >> 5, kk = k & 31;
    int lane = (n & 15) | ((kk >> 3) << 4);
    wf[(((kt * 18) + (n >> 4)) * 64 + lane) * 8 + (kk & 7)] = f2bf(v);
}

// ---------------- prep: frag weights, gate base, biases, mem frags ----------------
__global__ __launch_bounds__(256) void prep_kernel(
    const float* __restrict__ memv, const float* __restrict__ w_in,
    const float* __restrict__ b_in, const float* __restrict__ w_gate,
    const float* __restrict__ b_gate, unsigned char* __restrict__ ws)
{
    int bid = blockIdx.x, t = threadIdx.x;
    unsigned short* wfrag = (unsigned short*)(ws + WFRAG_OFF);
    const float* wg2 = w_gate + 128 * 128;   // rows 128..255 of w_gate

    if (bid < 256) {
        // combined weight: [w_in | w_in@W2 | w_in@mem^T] for 2 k-rows
        __shared__ float wrow[2][128];
        int k0 = bid * 2;
        wrow[t >> 7][t & 127] = w_in[(size_t)(k0 + (t >> 7)) * 128 + (t & 127)];
        __syncthreads();
        for (int kl = 0; kl < 2; ++kl) {
            int k = k0 + kl;
            float v;
            if (t < 128) {
                v = wrow[kl][t];
            } else {
                int d = t - 128;
                float acc = 0.f;
                #pragma unroll 8
                for (int j = 0; j < 128; ++j) acc += wrow[kl][j] * wg2[j * 128 + d];
                v = acc;
            }
            writefrag(wfrag, k, t, v);
            if (t < 32) {
                float acc = 0.f;
                #pragma unroll 8
                for (int d = 0; d < 128; ++d) acc += wrow[kl][d] * memv[t * 128 + d];
                writefrag(wfrag, k, 256 + t, acc);
            }
        }
    } else if (bid < 272) {
        // gb[s][d] = b_gate[d] + mem[s]@W1[:,d]
        int idx = (bid - 256) * 256 + t;      // 0..4095
        int s = idx >> 7, d = idx & 127;
        float acc = b_gate[d];
        #pragma unroll 8
        for (int k = 0; k < 128; ++k) acc += memv[s * 128 + k] * w_gate[k * 128 + d];
        ((float*)(ws + GB_OFF))[idx] = acc;
    } else {
        // biases + mem fragments
        if (t < 128) {
            float acc = 0.f;
            #pragma unroll 8
            for (int j = 0; j < 128; ++j) acc += b_in[j] * wg2[j * 128 + t];
            ((float*)(ws + BU_OFF))[t] = acc;
        }
        if (t < 32) {
            float acc = 0.f;
            #pragma unroll 8
            for (int d = 0; d < 128; ++d) acc += b_in[d] * memv[t * 128 + d];
            ((float*)(ws + BS_OFF))[t] = acc;
        }
        unsigned short* mfr = (unsigned short*)(ws + MEMFRAG_OFF);
        for (int idx = t; idx < 4096; idx += 256) {
            int s = idx >> 7, d = idx & 127;
            mfr[((d >> 4) * 64 + ((d & 15) | (((s >> 3) & 3) << 4))) * 8 + (s & 7)]
                = f2bf(memv[idx]);
        }
    }
}

// ---------------- main fused kernel: 512 blocks x 256 threads, 32 rows ----------------
__global__ __launch_bounds__(256, 2) void main_kernel(
    const float* __restrict__ x,
    const float* __restrict__ ln_g, const float* __restrict__ ln_b,
    const float* __restrict__ b_in, unsigned char* __restrict__ ws,
    float* __restrict__ out)
{
    __shared__ char smem[LDS_TOTAL] __attribute__((aligned(16)));

    int tid = threadIdx.x;
    int w = tid >> 6, l = tid & 63;
    int lane_lo = l & 15, lane_hi = l >> 4;
    int row_base = blockIdx.x * 32;

    // ===== Phase 1: LayerNorm -> swizzled bf16 A tile [32][512] =====
    const float4* x4 = (const float4*)x;
    float4 g0 = ((const float4*)ln_g)[l];
    float4 g1 = ((const float4*)ln_g)[l + 64];
    float4 q0 = ((const float4*)ln_b)[l];
    float4 q1 = ((const float4*)ln_b)[l + 64];
    #pragma unroll 4
    for (int i = 0; i < 8; ++i) {
        int r = w * 8 + i;
        float4 xa = x4[(size_t)(row_base + r) * 128 + l];
        float4 xb = x4[(size_t)(row_base + r) * 128 + 64 + l];
        float s1 = xa.x + xa.y + xa.z + xa.w + xb.x + xb.y + xb.z + xb.w;
        float s2 = xa.x*xa.x + xa.y*xa.y + xa.z*xa.z + xa.w*xa.w
                 + xb.x*xb.x + xb.y*xb.y + xb.z*xb.z + xb.w*xb.w;
        #pragma unroll
        for (int m = 1; m < 64; m <<= 1) {
            s1 += __shfl_xor(s1, m);
            s2 += __shfl_xor(s2, m);
        }
        float mu = s1 * (1.f / 512.f);
        float var = s2 * (1.f / 512.f) - mu * mu;
        float rs = rsqrtf(var + 1e-5f);
        float ya0 = (xa.x - mu) * rs * g0.x + q0.x;
        float ya1 = (xa.y - mu) * rs * g0.y + q0.y;
        float ya2 = (xa.z - mu) * rs * g0.z + q0.z;
        float ya3 = (xa.w - mu) * rs * g0.w + q0.w;
        float yb0 = (xb.x - mu) * rs * g1.x + q1.x;
        float yb1 = (xb.y - mu) * rs * g1.y + q1.y;
        float yb2 = (xb.z - mu) * rs * g1.z + q1.z;
        float yb3 = (xb.w - mu) * rs * g1.w + q1.w;
        unsigned long long pa =
            (unsigned long long)f2bf(ya0) | ((unsigned long long)f2bf(ya1) << 16) |
            ((unsigned long long)f2bf(ya2) << 32) | ((unsigned long long)f2bf(ya3) << 48);
        unsigned long long pb =
            (unsigned long long)f2bf(yb0) | ((unsigned long long)f2bf(yb1) << 16) |
            ((unsigned long long)f2bf(yb2) << 32) | ((unsigned long long)f2bf(yb3) << 48);
        int sw = (r & 7) << 4;
        *(unsigned long long*)(smem + ((r * 1024 + l * 8) ^ sw)) = pa;
        *(unsigned long long*)(smem + ((r * 1024 + 512 + l * 8) ^ sw)) = pb;
    }
    __syncthreads();

    // ===== Phase 2: MFMA GEMM [32 x 512] @ [512 x 288] =====
    int cnt = (w < 2) ? 5 : 4;
    int nts[5];
    #pragma unroll
    for (int i = 0; i < 4; ++i) nts[i] = w + i * 4;
    nts[4] = 16 + w;

    const bfrag_t* wf = (const bfrag_t*)(ws + WFRAG_OFF);
    int swa = (l & 7) << 4;
    int ab0 = (lane_lo) * 1024 + (lane_hi << 4);
    int ab1 = (16 + lane_lo) * 1024 + (lane_hi << 4);

    floatx4 acc[5][2];
    #pragma unroll
    for (int i = 0; i < 5; ++i)
        #pragma unroll
        for (int mt = 0; mt < 2; ++mt)
            acc[i][mt] = (floatx4){0.f, 0.f, 0.f, 0.f};

    bfrag_t acur0, acur1, anxt0, anxt1, bcur[5], bnxt[5];
    acur0 = *(const bfrag_t*)(smem + (ab0 ^ swa));
    acur1 = *(const bfrag_t*)(smem + (ab1 ^ swa));
    #pragma unroll
    for (int i = 0; i < 5; ++i)
        if (i < cnt) bcur[i] = wf[(0 * 18 + nts[i]) * 64 + l];

    for (int kt = 0; kt < 16; ++kt) {
        if (kt < 15) {
            int ko = (kt + 1) * 64;
            anxt0 = *(const bfrag_t*)(smem + ((ab0 + ko) ^ swa));
            anxt1 = *(const bfrag_t*)(smem + ((ab1 + ko) ^ swa));
            #pragma unroll
            for (int i = 0; i < 5; ++i)
                if (i < cnt) bnxt[i] = wf[((kt + 1) * 18 + nts[i]) * 64 + l];
        }
        #pragma unroll
        for (int i = 0; i < 5; ++i) {
            if (i < cnt) {
                acc[i][0] = __builtin_amdgcn_mfma_f32_16x16x32_bf16(acur0, bcur[i], acc[i][0], 0, 0, 0);
                acc[i][1] = __builtin_amdgcn_mfma_f32_16x16x32_bf16(acur1, bcur[i], acc[i][1], 0, 0, 0);
            }
        }
        acur0 = anxt0; acur1 = anxt1;
        #pragma unroll
        for (int i = 0; i < 5; ++i)
            if (i < cnt) bcur[i] = bnxt[i];
    }
    __syncthreads();   // A tile dead; region reused below

    // ===== Phase 3: epilogue -> xpfrag (bf16 frag), u (f32), scores (f32) =====
    {
        const float* bu = (const float*)(ws + BU_OFF);
        const float* bs = (const float*)(ws + BS_OFF);
        #pragma unroll
        for (int i = 0; i < 5; ++i) {
            if (i < cnt) {
                int n = nts[i] * 16 + lane_lo;
                #pragma unroll
                for (int mt = 0; mt < 2; ++mt) {
                    #pragma unroll
                    for (int r4 = 0; r4 < 4; ++r4) {
                        int row = mt * 16 + lane_hi * 4 + r4;
                        float v = acc[i][mt][r4];
                        if (i < 2) {                 // x_proj tiles 0..7 -> frag layout
                            float val = v + b_in[n];
                            int addr = XPFRAG_LDS +
                                (((n >> 4) * 64 + ((n & 15) | (((row >> 3) & 3) << 4))) * 8
                                 + (row & 7)) * 2;
                            *(unsigned short*)(smem + addr) = f2bf(val);
                        } else if (i < 4) {          // u tiles 8..15
                            int d = n - 128;
                            *(float*)(smem + U_OFF + (row * 128 + d) * 4) = v + bu[d];
                        } else {                     // score tiles 16..17
                            int s = n - 256;
                            *(float*)(smem + SC_OFF + (row * 32 + s) * 4) = v + bs[s];
                        }
                    }
                }
            }
        }
    }
    __syncthreads();

    // ===== Phase 4: softmax (8 rows per wave), store probs + probs^T (bf16) =====
    for (int i = 0; i < 8; ++i) {
        int r = w * 8 + i;
        int s = l & 31;
        float sc = *(const float*)(smem + SC_OFF + (r * 32 + s) * 4);
        float mx = sc;
        #pragma unroll
        for (int m = 1; m < 32; m <<= 1) mx = fmaxf(mx, __shfl_xor(mx, m));
        float e = __expf(sc - mx);
        float sum = e;
        #pragma unroll
        for (int m = 1; m < 32; m <<= 1) sum += __shfl_xor(sum, m);
        float p = e * __builtin_amdgcn_rcpf(sum);
        if (l < 32) {
            unsigned short pb = f2bf(p);
            *(unsigned short*)(smem + PR_OFF + (r * 40 + s) * 2) = pb;
            *(unsigned short*)(smem + PRT_OFF + (s * 40 + r) * 2) = pb;
        }
    }
    __syncthreads();

    float* accw = (float*)(ws + ACC_OFF + (size_t)(blockIdx.x & (NCOPY - 1)) * 32768);
    float* accg = accw + 4096;

    // ===== Phase 5: read-GEMM (probs@mem -> rc) + write-GEMM (probs^T@xp -> atomics) =====
    {
        bfrag_t pa[2], pat[2], bm[2], bx[2];
        #pragma unroll
        for (int mt = 0; mt < 2; ++mt) {
            pa[mt]  = *(const bfrag_t*)(smem + PR_OFF  + ((mt * 16 + lane_lo) * 40 + lane_hi * 8) * 2);
            pat[mt] = *(const bfrag_t*)(smem + PRT_OFF + ((mt * 16 + lane_lo) * 40 + lane_hi * 8) * 2);
        }
        const bfrag_t* mf = (const bfrag_t*)(ws + MEMFRAG_OFF);
        #pragma unroll
        for (int j = 0; j < 2; ++j) {
            int nt = 2 * w + j;
            bm[j] = mf[nt * 64 + l];
            bx[j] = *(const bfrag_t*)(smem + XPFRAG_LDS + (nt * 64 + l) * 16);
        }
        floatx4 rca[2][2], wa[2][2];
        #pragma unroll
        for (int j = 0; j < 2; ++j)
            #pragma unroll
            for (int mt = 0; mt < 2; ++mt) {
                rca[j][mt] = (floatx4){0.f, 0.f, 0.f, 0.f};
                wa[j][mt]  = (floatx4){0.f, 0.f, 0.f, 0.f};
                rca[j][mt] = __builtin_amdgcn_mfma_f32_16x16x32_bf16(pa[mt],  bm[j], rca[j][mt], 0, 0, 0);
                wa[j][mt]  = __builtin_amdgcn_mfma_f32_16x16x32_bf16(pat[mt], bx[j], wa[j][mt], 0, 0, 0);
            }
        #pragma unroll
        for (int j = 0; j < 2; ++j) {
            int nc = (2 * w + j) * 16 + lane_lo;
            #pragma unroll
            for (int mt = 0; mt < 2; ++mt) {
                #pragma unroll
                for (int r4 = 0; r4 < 4; ++r4) {
                    int row = mt * 16 + lane_hi * 4 + r4;
                    *(float*)(smem + RC_OFF + (row * 128 + nc) * 4) = rca[j][mt][r4];
                    __hip_atomic_fetch_add(&accw[row * 128 + nc], wa[j][mt][r4],
                                           __ATOMIC_RELAXED, __HIP_MEMORY_SCOPE_AGENT);
                }
            }
        }
    }
    __syncthreads();

    // ===== Phase 6: rc writeback (coalesced) + gate accumulation =====
    {
        const float4* rc4 = (const float4*)(smem + RC_OFF);
        float4* out4 = (float4*)out;
        #pragma unroll
        for (int q = 0; q < 4; ++q) {
            int idx = q * 256 + tid;              // 1024 float4s = 32 rows x 32
            int row = idx >> 5, c4 = idx & 31;
            out4[(size_t)(row_base + row) * 32 + c4] = rc4[idx];
        }
    }
    {
        int sbase = w * 8;
        const float* gb = (const float*)(ws + GB_OFF);
        float gbr0[8], gbr1[8], ag0[8], ag1[8];
        #pragma unroll
        for (int si = 0; si < 8; ++si) {
            gbr0[si] = gb[(sbase + si) * 128 + l];
            gbr1[si] = gb[(sbase + si) * 128 + l + 64];
            ag0[si] = 0.f; ag1[si] = 0.f;
        }
        for (int r = 0; r < 32; ++r) {
            float uv0 = *(const float*)(smem + U_OFF + (r * 128 + l) * 4);
            float uv1 = *(const float*)(smem + U_OFF + (r * 128 + l + 64) * 4);
            #pragma unroll
            for (int si = 0; si < 8; ++si) {
                ag0[si] += sigm(gbr0[si] + uv0);
                ag1[si] += sigm(gbr1[si] + uv1);
            }
        }
        #pragma unroll
        for (int si = 0; si < 8; ++si) {
            __hip_atomic_fetch_add(&accg[(sbase + si) * 128 + l],      ag0[si],
                                   __ATOMIC_RELAXED, __HIP_MEMORY_SCOPE_AGENT);
            __hip_atomic_fetch_add(&accg[(sbase + si) * 128 + l + 64], ag1[si],
                                   __ATOMIC_RELAXED, __HIP_MEMORY_SCOPE_AGENT);
        }
    }
}

// ---------------- finalize: reduce copies -> new_memory ----------------
__global__ __launch_bounds__(128) void fin_kernel(
    const float* __restrict__ memv, const unsigned char* __restrict__ ws,
    float* __restrict__ out2)
{
    int i = blockIdx.x * 128 + threadIdx.x;   // 32 blocks x 128 = 4096
    const float* base = (const float*)(ws + ACC_OFF);
    float aw = 0.f, ag = 0.f;
    #pragma unroll 8
    for (int c = 0; c < NCOPY; ++c) {
        aw += base[c * 8192 + i];
        ag += base[c * 8192 + 4096 + i];
    }
    ag *= (1.f / 16384.f);
    aw *= (1.f / 16384.f);
    out2[i] = memv[i] * (1.f - ag) + aw * ag;
}

// ---------------- launcher ----------------
extern "C" void kernel_launch(void* const* d_in, const int* in_sizes, int n_in,
                              void* d_out, int out_size, void* d_ws, size_t ws_size,
                              hipStream_t stream)
{
    (void)in_sizes; (void)n_in; (void)out_size; (void)ws_size;
    const float* x      = (const float*)d_in[0];
    const float* memv   = (const float*)d_in[1];
    const float* ln_g   = (const float*)d_in[2];
    const float* ln_b   = (const float*)d_in[3];
    const float* w_in   = (const float*)d_in[4];
    const float* b_in   = (const float*)d_in[5];
    const float* w_gate = (const float*)d_in[6];
    const float* b_gate = (const float*)d_in[7];
    float* out = (float*)d_out;
    unsigned char* ws = (unsigned char*)d_ws;

    hipMemsetAsync(ws + ACC_OFF, 0, NCOPY * 32768, stream);
    hipLaunchKernelGGL(prep_kernel, dim3(273), dim3(256), 0, stream,
                       memv, w_in, b_in, w_gate, b_gate, ws);
    hipLaunchKernelGGL(main_kernel, dim3(512), dim3(256), 0, stream,
                       x, ln_g, ln_b, b_in, ws, out);
    hipLaunchKernelGGL(fin_kernel, dim3(32), dim3(128), 0, stream,
                       memv, ws, out + 2097152);
}